// Round 6
// baseline (211.596 us; speedup 1.0000x reference)
//
#include <hip/hip_runtime.h>
#include <hip/hip_bf16.h>

#define S_LEN 1024
#define DM 256
#define NTOK 32768

typedef __attribute__((ext_vector_type(8))) short short8;
typedef __attribute__((ext_vector_type(4))) short s16x4;
typedef __attribute__((ext_vector_type(4))) float f32x4;

__device__ __forceinline__ float bf2f(unsigned short u) {
    return __uint_as_float(((unsigned int)u) << 16);
}
__device__ __forceinline__ unsigned short f2bf(float f) {
    unsigned int x = __float_as_uint(f);
    return (unsigned short)((x + 0x7fffu + ((x >> 16) & 1u)) >> 16);  // RNE
}

// ---- bf16 weight convert (1 MB/dir x 2 layers) -------------------------
__global__ void convert_w_kernel(const float* __restrict__ WF,
                                 const float* __restrict__ WB,
                                 short* __restrict__ WbF,
                                 short* __restrict__ WbB) {
    int dir = blockIdx.y;
    const float* src = dir ? WB : WF;
    short* dst = dir ? WbB : WbF;
    int idx = blockIdx.x * blockDim.x + threadIdx.x;  // 65536 threads x 8
    const float4* p = (const float4*)src + (size_t)idx * 2;
    float4 a = p[0], b = p[1];
    short8 v;
    v[0] = (short)f2bf(a.x); v[1] = (short)f2bf(a.y);
    v[2] = (short)f2bf(a.z); v[3] = (short)f2bf(a.w);
    v[4] = (short)f2bf(b.x); v[5] = (short)f2bf(b.y);
    v[6] = (short)f2bf(b.z); v[7] = (short)f2bf(b.w);
    ((short8*)dst)[idx] = v;
}

// ---- GEMM: 64x512x256, A from swizzled LDS, W [512][256] from L2 -------
// Explicit double-buffer on the W (B-operand) fragments to hide L2 latency.
__device__ __forceinline__ void gemm_tile(const short* Alds, const short* __restrict__ W,
                                          f32x4 acc[4][4], int wv, int l) {
    int cb0 = wv * 32;
    int krow = l >> 4;
    int lc = l & 15;
    const short* wp[4];
    wp[0] = W + (size_t)(cb0 + lc) * DM + krow * 8;
    wp[1] = W + (size_t)(cb0 + 16 + lc) * DM + krow * 8;
    wp[2] = W + (size_t)(256 + cb0 + lc) * DM + krow * 8;
    wp[3] = W + (size_t)(256 + cb0 + 16 + lc) * DM + krow * 8;

    short8 bcur[4], bnxt[4];
#pragma unroll
    for (int i = 0; i < 4; i++) bcur[i] = *(const short8*)(wp[i]);

#pragma unroll
    for (int kk = 0; kk < 8; kk++) {
        if (kk < 7) {
#pragma unroll
            for (int i = 0; i < 4; i++) bnxt[i] = *(const short8*)(wp[i] + (kk + 1) * 32);
        }
        int k = kk * 32 + krow * 8;
        short8 afr[4];
#pragma unroll
        for (int mf = 0; mf < 4; mf++) {
            int row = mf * 16 + lc;
            int sidx = row * DM + (((k >> 3) ^ (row & 7)) << 3);  // k&7==0
            afr[mf] = *(const short8*)(Alds + sidx);
        }
#pragma unroll
        for (int mf = 0; mf < 4; mf++)
#pragma unroll
            for (int nf = 0; nf < 4; nf++)
                acc[mf][nf] = __builtin_amdgcn_mfma_f32_16x16x32_bf16(
                    afr[mf], bcur[nf], acc[mf][nf], 0, 0, 0);
        if (kk < 7) {
#pragma unroll
            for (int i = 0; i < 4; i++) bcur[i] = bnxt[i];
        }
    }
}

// ---- highway epilogue: y = g*x + (1-g)*relu(nl), result -> dst (LDS) ---
__device__ __forceinline__ void hw_epilogue(f32x4 acc[4][4], const float* __restrict__ bias,
                                            const short* src, short* dst, int wv, int l) {
    int cb0 = wv * 32, krow = l >> 4, lc = l & 15;
#pragma unroll
    for (int mf = 0; mf < 4; mf++) {
#pragma unroll
        for (int nfp = 0; nfp < 2; nfp++) {
            int e = cb0 + nfp * 16 + lc;
            float be = bias[e];
            float bg = bias[e + 256];
            f32x4 nl = acc[mf][nfp];
            f32x4 gt = acc[mf][nfp + 2];
#pragma unroll
            for (int r = 0; r < 4; r++) {
                int trow = mf * 16 + krow * 4 + r;
                int sx = trow * DM + (((e >> 3) ^ (trow & 7)) << 3) + (e & 7);
                float xe = bf2f((unsigned short)src[sx]);
                float nlv = nl[r] + be;
                float gv = gt[r] + bg;
                float g = 1.0f / (1.0f + __expf(-gv));
                float y = g * xe + (1.0f - g) * fmaxf(nlv, 0.0f);
                dst[sx] = (short)f2bf(y);
            }
        }
    }
}

// ---- fused per-layer kernel: taps -> hw1 -> hw2 -> coalesced writeout --
// grid (512, 2): 64-token tiles x direction. 512 threads (8 waves).
template <int IN_F32, int LAST>
__global__ __launch_bounds__(512, 4)
void layer_kernel(const void* xinF_, const void* xinB_,
                  const float* __restrict__ fpad, const float* __restrict__ bpad,
                  const float* __restrict__ fw5, const float* __restrict__ bw5,
                  const short* __restrict__ WF_, const short* __restrict__ WB_,
                  const float* __restrict__ bF_, const float* __restrict__ bB_,
                  short* __restrict__ xoutF, short* __restrict__ xoutB,
                  float* __restrict__ outp) {
    int dir = blockIdx.y;
    const void* xin = dir ? xinB_ : xinF_;
    const short* W = dir ? WB_ : WF_;
    const float* bias = dir ? bB_ : bF_;
    short* xout = dir ? xoutB : xoutF;
    const float* pad = dir ? bpad : fpad;
    const float* w5g = dir ? bw5 : fw5;
    int ch0 = dir ? 256 : 0;

    __shared__ __align__(16) short As[64 * DM];  // 32 KB, XOR-swizzled (16B chunk ^ row&7)
    __shared__ __align__(16) short Bs[64 * DM];  // 32 KB

    int tid = threadIdx.x;
    int wv = tid >> 6;
    int l = tid & 63;
    int t0 = blockIdx.x * 64;

    float wj5[5];
#pragma unroll
    for (int j = 0; j < 5; j++) wj5[j] = w5g[j];

    // ---- phase 1: 5-tap conv directly into swizzled LDS tile ----
#pragma unroll
    for (int p = 0; p < 4; p++) {
        int pos = p * 512 + tid;       // 2048 (row, 16B-chunk) positions
        int row = pos >> 5;
        int c = pos & 31;
        int d0 = c << 3;
        int tg = t0 + row;
        int s = tg & (S_LEN - 1);
        float a8[8];
#pragma unroll
        for (int i = 0; i < 8; i++) a8[i] = 0.0f;
#pragma unroll
        for (int j = 0; j < 5; j++) {
            float wj = wj5[j];
            bool use_pad = (dir == 0) ? (s + j < 4) : (s + j >= S_LEN);
            if (use_pad) {
                const float* pf = (dir == 0) ? (pad + (size_t)(s + j) * DM + d0)
                                             : (pad + (size_t)(s + j - S_LEN) * DM + d0);
                const float4* q = (const float4*)pf;
                float4 a = q[0], b = q[1];
                a8[0] += wj * a.x; a8[1] += wj * a.y; a8[2] += wj * a.z; a8[3] += wj * a.w;
                a8[4] += wj * b.x; a8[5] += wj * b.y; a8[6] += wj * b.z; a8[7] += wj * b.w;
            } else {
                long st = (dir == 0) ? ((long)tg + j - 4) : ((long)tg + j);
                if (IN_F32) {
                    const float4* q = (const float4*)((const float*)xin + st * DM + d0);
                    float4 a = q[0], b = q[1];
                    a8[0] += wj * a.x; a8[1] += wj * a.y; a8[2] += wj * a.z; a8[3] += wj * a.w;
                    a8[4] += wj * b.x; a8[5] += wj * b.y; a8[6] += wj * b.z; a8[7] += wj * b.w;
                } else {
                    short8 v = *(const short8*)((const short*)xin + st * DM + d0);
#pragma unroll
                    for (int i = 0; i < 8; i++) a8[i] += wj * bf2f((unsigned short)v[i]);
                }
            }
        }
        short8 o;
#pragma unroll
        for (int i = 0; i < 8; i++) o[i] = (short)f2bf(a8[i]);
        *(short8*)(As + row * DM + ((c ^ (row & 7)) << 3)) = o;
    }
    __syncthreads();

    // ---- phase 2: highway sub-layer 0: GEMM(As) + gate -> Bs ----
    f32x4 acc[4][4];
    f32x4 zero = {0.f, 0.f, 0.f, 0.f};
#pragma unroll
    for (int i = 0; i < 4; i++)
#pragma unroll
        for (int j = 0; j < 4; j++) acc[i][j] = zero;
    gemm_tile(As, W, acc, wv, l);
    hw_epilogue(acc, bias, As, Bs, wv, l);   // reads As, writes Bs: no hazard
    __syncthreads();

    // ---- phase 3: highway sub-layer 1: GEMM(Bs) + gate -> Bs in place ----
#pragma unroll
    for (int i = 0; i < 4; i++)
#pragma unroll
        for (int j = 0; j < 4; j++) acc[i][j] = zero;
    gemm_tile(Bs, W + 512 * DM, acc, wv, l);
    __syncthreads();                         // all Bs reads done before in-place write
    hw_epilogue(acc, bias + 512, Bs, Bs, wv, l);
    __syncthreads();

    // ---- phase 4: coalesced writeout from Bs ----
    // fp32 out: one full 512B LDS row per wave-instr; 1KB contiguous global store
#pragma unroll
    for (int it = 0; it < 8; it++) {
        int pos = it * 512 + tid;            // 4096 float4 positions
        int row = pos >> 6;
        int c4 = (pos & 63) << 2;
        int sx = row * DM + (((c4 >> 3) ^ (row & 7)) << 3) + (c4 & 7);
        s16x4 v = *(const s16x4*)(Bs + sx);
        float4 o;
        o.x = bf2f((unsigned short)v[0]);
        o.y = bf2f((unsigned short)v[1]);
        o.z = bf2f((unsigned short)v[2]);
        o.w = bf2f((unsigned short)v[3]);
        *(float4*)(outp + (size_t)(t0 + row) * 512 + ch0 + c4) = o;
    }
    if (!LAST) {
        // bf16 state: 512B contiguous per row
#pragma unroll
        for (int it = 0; it < 4; it++) {
            int pos = it * 512 + tid;        // 2048 short8 positions
            int row = pos >> 5;
            int c8 = (pos & 31) << 3;
            int sx = row * DM + (((c8 >> 3) ^ (row & 7)) << 3);
            short8 v = *(const short8*)(Bs + sx);
            *(short8*)(xout + (size_t)(t0 + row) * DM + c8) = v;
        }
    }
}

extern "C" void kernel_launch(void* const* d_in, const int* in_sizes, int n_in,
                              void* d_out, int out_size, void* d_ws, size_t ws_size,
                              hipStream_t stream) {
    const float* inputs = (const float*)d_in[0];
    const float* fwd_pad = (const float*)d_in[1];
    const float* bwd_pad = (const float*)d_in[2];
    const float* fwd_w = (const float*)d_in[3];
    const float* bwd_w = (const float*)d_in[4];
    const float* fwd_hw_W = (const float*)d_in[5];
    const float* fwd_hw_b = (const float*)d_in[6];
    const float* bwd_hw_W = (const float*)d_in[7];
    const float* bwd_hw_b = (const float*)d_in[8];
    float* out = (float*)d_out;

    const size_t XN = (size_t)NTOK * DM;          // 8,388,608 bf16 per state buf
    const size_t WN = (size_t)2 * 2 * 512 * 256;  // per-dir bf16 weight elems
    short* curF = (short*)d_ws;
    short* curB = curF + XN;
    short* WbF = curB + XN;
    short* WbB = WbF + WN;  // total ws: 32 MB state + 4 MB weights

    convert_w_kernel<<<dim3(256, 2), dim3(256), 0, stream>>>(fwd_hw_W, bwd_hw_W, WbF, WbB);

    // layer 0: reads fp32 inputs (both dirs), writes bf16 state + fp32 out
    layer_kernel<1, 0><<<dim3(512, 2), dim3(512), 0, stream>>>(
        (const void*)inputs, (const void*)inputs,
        fwd_pad, bwd_pad, fwd_w, bwd_w,
        WbF, WbB, fwd_hw_b, bwd_hw_b,
        curF, curB, out);

    // layer 1: reads bf16 state, writes fp32 out only
    layer_kernel<0, 1><<<dim3(512, 2), dim3(512), 0, stream>>>(
        (const void*)curF, (const void*)curB,
        fwd_pad + 4 * DM, bwd_pad + 4 * DM, fwd_w + 5, bwd_w + 5,
        WbF + 2 * 512 * DM, WbB + 2 * 512 * DM,
        fwd_hw_b + 1024, bwd_hw_b + 1024,
        nullptr, nullptr, out + (size_t)NTOK * 512);
}